// Round 1
// baseline (14111.119 us; speedup 1.0000x reference)
//
#include <hip/hip_runtime.h>
#include <cmath>

#define B 64
#define S 4096
#define NI 16
#define H 128
#define G 384   // 3*H
#define F 144   // H + NI

__device__ __forceinline__ float sigmoidf_(float x) {
    return 1.0f / (1.0f + __expf(-x));
}

// ---------------------------------------------------------------------------
// Layer 0 GRU: one workgroup per batch element, 384 threads (one per gate row).
// Weights live in VGPRs; h lives in LDS; x[t+1] prefetched into regs.
// ---------------------------------------------------------------------------
__global__ __launch_bounds__(384)
void gru_layer0(const float* __restrict__ x,
                const float* __restrict__ w_ih, const float* __restrict__ w_hh,
                const float* __restrict__ b_ih, const float* __restrict__ b_hh,
                float* __restrict__ h_out)
{
    __shared__ float sX[NI];
    __shared__ float sH[H];
    __shared__ float sI[G];
    __shared__ float sHh[G];

    const int b = blockIdx.x;
    const int j = threadIdx.x;

    float wih[NI];
#pragma unroll
    for (int k = 0; k < NI; k++) wih[k] = w_ih[j * NI + k];
    float whh[H];
#pragma unroll
    for (int k = 0; k < H; k++) whh[k] = w_hh[j * H + k];
    const float bi = b_ih[j];
    const float bh = b_hh[j];

    if (j < H) sH[j] = 0.0f;
    const float* xb = x + (size_t)b * S * NI;
    float xpre = (j < NI) ? xb[j] : 0.0f;
    float* hob = h_out + (size_t)b * S * H;
    __syncthreads();

    for (int t = 0; t < S; t++) {
        if (j < NI) sX[j] = xpre;
        __syncthreads();
        // prefetch next timestep's input while we compute
        if (j < NI && (t + 1) < S) xpre = xb[(size_t)(t + 1) * NI + j];

        float ai = bi;
#pragma unroll
        for (int k = 0; k < NI; k++) ai += sX[k] * wih[k];

        float a0 = 0.f, a1 = 0.f, a2 = 0.f, a3 = 0.f;
#pragma unroll
        for (int k = 0; k < H; k += 4) {
            a0 += sH[k + 0] * whh[k + 0];
            a1 += sH[k + 1] * whh[k + 1];
            a2 += sH[k + 2] * whh[k + 2];
            a3 += sH[k + 3] * whh[k + 3];
        }
        float ah = bh + ((a0 + a1) + (a2 + a3));

        sI[j] = ai;
        sHh[j] = ah;
        __syncthreads();

        if (j < H) {
            float r = sigmoidf_(sI[j] + sHh[j]);
            float z = sigmoidf_(sI[H + j] + sHh[H + j]);
            float n = tanhf(sI[2 * H + j] + r * sHh[2 * H + j]);
            float hn = (1.0f - z) * n + z * sH[j];
            sH[j] = hn;
            hob[(size_t)t * H + j] = hn;
        }
        __syncthreads();
    }
}

// ---------------------------------------------------------------------------
// Layer 1 GRU: one workgroup per batch, 768 threads.
//  threads [0,384): gi1 row j  (w_ih1 in regs, input = h0[t] broadcast via LDS)
//  threads [384,768): gh1 row j (w_hh1 in regs, input = h1 state in LDS)
// h0 buffer is overwritten in place with h1 (read of [b,t] precedes write).
// ---------------------------------------------------------------------------
__global__ __launch_bounds__(768)
void gru_layer1(const float* __restrict__ w_ih, const float* __restrict__ w_hh,
                const float* __restrict__ b_ih, const float* __restrict__ b_hh,
                float* __restrict__ hbuf)
{
    __shared__ float sHin[H];
    __shared__ float sH1[H];
    __shared__ float sI[G];
    __shared__ float sHh[G];

    const int b = blockIdx.x;
    const int tid = threadIdx.x;
    const bool gA = (tid < G);
    const int j = gA ? tid : (tid - G);

    const float* wsrc = gA ? (w_ih + (size_t)j * H) : (w_hh + (size_t)j * H);
    float w[H];
#pragma unroll
    for (int k = 0; k < H; k++) w[k] = wsrc[k];
    const float bias_ = gA ? b_ih[j] : b_hh[j];

    float* hb = hbuf + (size_t)b * S * H;
    if (tid < H) sH1[tid] = 0.0f;
    float pre = (tid < H) ? hb[tid] : 0.0f;
    __syncthreads();

    for (int t = 0; t < S; t++) {
        if (tid < H) sHin[tid] = pre;
        __syncthreads();
        // prefetch h0 for next step (hidden under the dot products)
        if (tid < H && (t + 1) < S) pre = hb[(size_t)(t + 1) * H + tid];

        const float* src = gA ? sHin : sH1;
        float a0 = 0.f, a1 = 0.f, a2 = 0.f, a3 = 0.f;
#pragma unroll
        for (int k = 0; k < H; k += 4) {
            a0 += src[k + 0] * w[k + 0];
            a1 += src[k + 1] * w[k + 1];
            a2 += src[k + 2] * w[k + 2];
            a3 += src[k + 3] * w[k + 3];
        }
        float acc = bias_ + ((a0 + a1) + (a2 + a3));
        if (gA) sI[j] = acc; else sHh[j] = acc;
        __syncthreads();

        if (tid < H) {
            float r = sigmoidf_(sI[tid] + sHh[tid]);
            float z = sigmoidf_(sI[H + tid] + sHh[H + tid]);
            float n = tanhf(sI[2 * H + tid] + r * sHh[2 * H + tid]);
            float hn = (1.0f - z) * n + z * sH1[tid];
            sH1[tid] = hn;
            hb[(size_t)t * H + tid] = hn;   // overwrite h0[b,t] with h1[b,t]
        }
        __syncthreads();
    }
}

// ---------------------------------------------------------------------------
// MLP head, batched over all B*S rows. One wave (64 threads) per block; lane m
// owns hidden unit m (w1 row in 144 VGPRs). Rows double-buffered through LDS.
// ---------------------------------------------------------------------------
__global__ __launch_bounds__(64)
void head_kernel(const float* __restrict__ h1, const float* __restrict__ x,
                 const float* __restrict__ w1, const float* __restrict__ b1,
                 const float* __restrict__ w2, const float* __restrict__ b2,
                 float* __restrict__ inc, int rows_per_blk)
{
    __shared__ float sC[2][F];
    const int lane = threadIdx.x;

    float wr[F];
#pragma unroll
    for (int f = 0; f < F; f++) wr[f] = w1[lane * F + f];
    const float b1v = b1[lane];
    const float w2v = w2[lane];
    const float b2v = b2[0];

    const int row0 = blockIdx.x * rows_per_blk;

    // stage first row
    {
        const int r = row0;
        sC[0][lane]      = h1[(size_t)r * H + lane];
        sC[0][64 + lane] = h1[(size_t)r * H + 64 + lane];
        if (lane < NI) sC[0][H + lane] = x[(size_t)r * NI + lane];
    }
    __syncthreads();

    for (int i = 0; i < rows_per_blk; i++) {
        const int row = row0 + i;
        const int cur = i & 1;
        const int nxt = cur ^ 1;

        float p0 = 0.f, p1 = 0.f, p2 = 0.f;
        if (i + 1 < rows_per_blk) {
            const int rn = row + 1;
            p0 = h1[(size_t)rn * H + lane];
            p1 = h1[(size_t)rn * H + 64 + lane];
            if (lane < NI) p2 = x[(size_t)rn * NI + lane];
        }

        float acc = b1v;
#pragma unroll
        for (int f = 0; f < F; f++) acc += sC[cur][f] * wr[f];

        if (i + 1 < rows_per_blk) {
            sC[nxt][lane]      = p0;
            sC[nxt][64 + lane] = p1;
            if (lane < NI) sC[nxt][H + lane] = p2;
        }

        float v = fmaxf(acc, 0.0f) * w2v;
#pragma unroll
        for (int off = 32; off > 0; off >>= 1) v += __shfl_xor(v, off, 64);

        if (lane == 0) inc[row] = tanhf(v + b2v) * 0.125f;
        __syncthreads();
    }
}

// ---------------------------------------------------------------------------
// Inclusive cumsum over S per batch + initial offset. One block per batch.
// ---------------------------------------------------------------------------
__global__ __launch_bounds__(256)
void cumsum_kernel(const float* __restrict__ inc, const float* __restrict__ init,
                   float* __restrict__ out)
{
    __shared__ float sW[4];
    const int b = blockIdx.x;
    const int tid = threadIdx.x;
    const int lane = tid & 63;
    const int wid = tid >> 6;

    const float* ib = inc + (size_t)b * S;
    float v[16];
#pragma unroll
    for (int i = 0; i < 16; i++) v[i] = ib[tid * 16 + i];

    float run = 0.f;
#pragma unroll
    for (int i = 0; i < 16; i++) { run += v[i]; v[i] = run; }

    // inclusive shuffle scan of per-thread totals within the wave
    float t = run;
#pragma unroll
    for (int off = 1; off < 64; off <<= 1) {
        float u = __shfl_up(t, off, 64);
        if (lane >= off) t += u;
    }
    const float excl = t - run;
    if (lane == 63) sW[wid] = t;
    __syncthreads();

    float wo = 0.f;
#pragma unroll
    for (int w = 0; w < 4; w++) if (w < wid) wo += sW[w];

    const float prefix = wo + excl + init[0];
    float* ob = out + (size_t)b * S;
#pragma unroll
    for (int i = 0; i < 16; i++) ob[tid * 16 + i] = prefix + v[i];
}

// ---------------------------------------------------------------------------
extern "C" void kernel_launch(void* const* d_in, const int* in_sizes, int n_in,
                              void* d_out, int out_size, void* d_ws, size_t ws_size,
                              hipStream_t stream)
{
    const float* x     = (const float*)d_in[0];
    const float* w_ih0 = (const float*)d_in[1];
    const float* w_hh0 = (const float*)d_in[2];
    const float* b_ih0 = (const float*)d_in[3];
    const float* b_hh0 = (const float*)d_in[4];
    const float* w_ih1 = (const float*)d_in[5];
    const float* w_hh1 = (const float*)d_in[6];
    const float* b_ih1 = (const float*)d_in[7];
    const float* b_hh1 = (const float*)d_in[8];
    const float* w1    = (const float*)d_in[9];
    const float* b1    = (const float*)d_in[10];
    const float* w2    = (const float*)d_in[11];
    const float* b2    = (const float*)d_in[12];
    const float* init  = (const float*)d_in[13];
    float* out = (float*)d_out;

    float* hbuf   = (float*)d_ws;                 // B*S*H fp32 = 134 MB
    float* incbuf = hbuf + (size_t)B * S * H;     // B*S fp32  = 1 MB

    hipLaunchKernelGGL(gru_layer0, dim3(B), dim3(G), 0, stream,
                       x, w_ih0, w_hh0, b_ih0, b_hh0, hbuf);
    hipLaunchKernelGGL(gru_layer1, dim3(B), dim3(2 * G), 0, stream,
                       w_ih1, w_hh1, b_ih1, b_hh1, hbuf);
    hipLaunchKernelGGL(head_kernel, dim3((B * S) / 128), dim3(64), 0, stream,
                       hbuf, x, w1, b1, w2, b2, incbuf, 128);
    hipLaunchKernelGGL(cumsum_kernel, dim3(B), dim3(256), 0, stream,
                       incbuf, init, out);
}

// Round 2
// 6984.254 us; speedup vs baseline: 2.0204x; 2.0204x over previous
//
#include <hip/hip_runtime.h>
#include <cmath>

#define B 64
#define S 4096
#define NI 16
#define H 128
#define G 384   // 3*H
#define F 144   // H + NI

__device__ __forceinline__ float sigmoidf_(float x) {
    return 1.0f / (1.0f + __expf(-x));
}

// 2-stage quad butterfly sum via DPP quad_perm (VALU pipe, not LDS pipe).
// After this every lane of the quad holds the full 4-lane sum.
__device__ __forceinline__ float quad_reduce(float v) {
    int t1 = __builtin_amdgcn_mov_dpp(__float_as_int(v), 0xB1, 0xf, 0xf, true); // xor 1
    v += __int_as_float(t1);
    int t2 = __builtin_amdgcn_mov_dpp(__float_as_int(v), 0x4E, 0xf, 0xf, true); // xor 2
    v += __int_as_float(t2);
    return v;
}

// ---------------------------------------------------------------------------
// Layer 0 GRU: 1 WG/batch, 384 threads = 6 waves, 64 gate-rows per wave.
// Quad-split: lane m of each quad owns k in [32m,32m+32) for 4 rows.
// LDS reads: 8 ds_read_b128 (h) + 1 (x) per lane per step, bank-staggered.
// ---------------------------------------------------------------------------
__global__ __launch_bounds__(384)
void gru_layer0(const float* __restrict__ x,
                const float* __restrict__ w_ih, const float* __restrict__ w_hh,
                const float* __restrict__ b_ih, const float* __restrict__ b_hh,
                float* __restrict__ h_out)
{
    __shared__ float sX[NI];
    __shared__ float sH[H];
    __shared__ float sI[G];
    __shared__ float sHh[G];

    const int b    = blockIdx.x;
    const int tid  = threadIdx.x;
    const int wave = tid >> 6;
    const int lane = tid & 63;
    const int q    = lane >> 2;
    const int m    = lane & 3;
    const int m2   = 2 * m;
    const int rowBase = wave * 64 + q * 4;       // this quad's 4 rows

    // h-weights: 4 rows x 32 k, stored in the staggered read order
    float wh[128];
#pragma unroll
    for (int a = 0; a < 4; a++) {
        const float* wr = w_hh + (size_t)(rowBase + a) * H + 32 * m;
#pragma unroll
        for (int i = 0; i < 8; i++) {
            const int o = ((i + m2) & 7) * 4;
            const float4 wv = *(const float4*)(wr + o);
            wh[a * 32 + i * 4 + 0] = wv.x;
            wh[a * 32 + i * 4 + 1] = wv.y;
            wh[a * 32 + i * 4 + 2] = wv.z;
            wh[a * 32 + i * 4 + 3] = wv.w;
        }
    }
    // x-weights: 4 rows x 4 k (lane m owns k in [4m,4m+4))
    float wx[16];
#pragma unroll
    for (int a = 0; a < 4; a++) {
        const float4 wv = *(const float4*)(w_ih + (size_t)(rowBase + a) * NI + 4 * m);
        wx[a * 4 + 0] = wv.x; wx[a * 4 + 1] = wv.y;
        wx[a * 4 + 2] = wv.z; wx[a * 4 + 3] = wv.w;
    }
    const float bi = b_ih[rowBase + m];   // bias of the row this lane will write
    const float bh = b_hh[rowBase + m];

    const float* xb  = x + (size_t)b * S * NI;
    float*       hob = h_out + (size_t)b * S * H;

    float hprev = 0.0f;                   // own h state (tid < H)
    if (tid < H) sH[tid] = 0.0f;
    if (tid < NI) sX[tid] = xb[tid];
    float prex = (tid < NI) ? xb[NI + tid] : 0.0f;   // x[1]
    __syncthreads();

    const float4* srcH = (const float4*)sH + 8 * m;
    const float4* srcX = (const float4*)sX + m;

    for (int t = 0; t < S; t++) {
        float h0 = 0.f, h1 = 0.f, h2 = 0.f, h3 = 0.f;
#pragma unroll
        for (int i = 0; i < 8; i++) {
            const int f = (i + m2) & 7;
            const float4 h4 = srcH[f];
            h0 = fmaf(h4.x, wh[0*32+i*4+0], h0); h0 = fmaf(h4.y, wh[0*32+i*4+1], h0);
            h0 = fmaf(h4.z, wh[0*32+i*4+2], h0); h0 = fmaf(h4.w, wh[0*32+i*4+3], h0);
            h1 = fmaf(h4.x, wh[1*32+i*4+0], h1); h1 = fmaf(h4.y, wh[1*32+i*4+1], h1);
            h1 = fmaf(h4.z, wh[1*32+i*4+2], h1); h1 = fmaf(h4.w, wh[1*32+i*4+3], h1);
            h2 = fmaf(h4.x, wh[2*32+i*4+0], h2); h2 = fmaf(h4.y, wh[2*32+i*4+1], h2);
            h2 = fmaf(h4.z, wh[2*32+i*4+2], h2); h2 = fmaf(h4.w, wh[2*32+i*4+3], h2);
            h3 = fmaf(h4.x, wh[3*32+i*4+0], h3); h3 = fmaf(h4.y, wh[3*32+i*4+1], h3);
            h3 = fmaf(h4.z, wh[3*32+i*4+2], h3); h3 = fmaf(h4.w, wh[3*32+i*4+3], h3);
        }
        const float4 xv = *srcX;
        float i0 = 0.f, i1 = 0.f, i2 = 0.f, i3 = 0.f;
        i0 = fmaf(xv.x, wx[0], i0); i0 = fmaf(xv.y, wx[1], i0);
        i0 = fmaf(xv.z, wx[2], i0); i0 = fmaf(xv.w, wx[3], i0);
        i1 = fmaf(xv.x, wx[4], i1); i1 = fmaf(xv.y, wx[5], i1);
        i1 = fmaf(xv.z, wx[6], i1); i1 = fmaf(xv.w, wx[7], i1);
        i2 = fmaf(xv.x, wx[8], i2); i2 = fmaf(xv.y, wx[9], i2);
        i2 = fmaf(xv.z, wx[10], i2); i2 = fmaf(xv.w, wx[11], i2);
        i3 = fmaf(xv.x, wx[12], i3); i3 = fmaf(xv.y, wx[13], i3);
        i3 = fmaf(xv.z, wx[14], i3); i3 = fmaf(xv.w, wx[15], i3);

        const float rh0 = quad_reduce(h0), rh1 = quad_reduce(h1);
        const float rh2 = quad_reduce(h2), rh3 = quad_reduce(h3);
        const float ri0 = quad_reduce(i0), ri1 = quad_reduce(i1);
        const float ri2 = quad_reduce(i2), ri3 = quad_reduce(i3);

        const float vh = ((m == 0) ? rh0 : (m == 1) ? rh1 : (m == 2) ? rh2 : rh3) + bh;
        const float vi = ((m == 0) ? ri0 : (m == 1) ? ri1 : (m == 2) ? ri2 : ri3) + bi;
        sI[rowBase + m]  = vi;
        sHh[rowBase + m] = vh;
        __syncthreads();                       // gates ready

        if (tid < H) {
            const float r  = sigmoidf_(sI[tid] + sHh[tid]);
            const float z  = sigmoidf_(sI[H + tid] + sHh[H + tid]);
            const float n  = tanhf(sI[2 * H + tid] + r * sHh[2 * H + tid]);
            const float hn = (1.0f - z) * n + z * hprev;
            hprev = hn;
            sH[tid] = hn;
            hob[(size_t)t * H + tid] = hn;
        }
        if (tid < NI) {
            sX[tid] = prex;                    // x[t+1]
            if (t + 2 < S) prex = xb[(size_t)(t + 2) * NI + tid];
        }
        __syncthreads();                       // state ready for next step
    }
}

// ---------------------------------------------------------------------------
// Layer 1 GRU: 1 WG/batch, 768 threads = 12 waves.
// Waves 0..5: gi rows (input = h0[t] in sHin); waves 6..11: gh rows (sH1).
// Same quad-split layout. h0 buffer overwritten in place with h1.
// ---------------------------------------------------------------------------
__global__ __launch_bounds__(768)
void gru_layer1(const float* __restrict__ w_ih, const float* __restrict__ w_hh,
                const float* __restrict__ b_ih, const float* __restrict__ b_hh,
                float* __restrict__ hbuf)
{
    __shared__ float sHin[H];
    __shared__ float sH1[H];
    __shared__ float sI[G];
    __shared__ float sHh[G];

    const int b    = blockIdx.x;
    const int tid  = threadIdx.x;
    const int wave = tid >> 6;
    const int lane = tid & 63;
    const int q    = lane >> 2;
    const int m    = lane & 3;
    const int m2   = 2 * m;
    const bool isGi = (wave < 6);
    const int rowBase = (isGi ? wave : wave - 6) * 64 + q * 4;

    const float* Wsrc = isGi ? w_ih : w_hh;
    float wreg[128];
#pragma unroll
    for (int a = 0; a < 4; a++) {
        const float* wr = Wsrc + (size_t)(rowBase + a) * H + 32 * m;
#pragma unroll
        for (int i = 0; i < 8; i++) {
            const int o = ((i + m2) & 7) * 4;
            const float4 wv = *(const float4*)(wr + o);
            wreg[a * 32 + i * 4 + 0] = wv.x;
            wreg[a * 32 + i * 4 + 1] = wv.y;
            wreg[a * 32 + i * 4 + 2] = wv.z;
            wreg[a * 32 + i * 4 + 3] = wv.w;
        }
    }
    const float bias_ = isGi ? b_ih[rowBase + m] : b_hh[rowBase + m];

    float* hb = hbuf + (size_t)b * S * H;
    float hprev = 0.0f;
    if (tid < H) { sH1[tid] = 0.0f; sHin[tid] = hb[tid]; }
    float pre = (tid < H) ? hb[H + tid] : 0.0f;   // h0[1]
    __syncthreads();

    const float4* src4 = (const float4*)(isGi ? sHin : sH1) + 8 * m;

    for (int t = 0; t < S; t++) {
        float a0 = 0.f, a1 = 0.f, a2 = 0.f, a3 = 0.f;
#pragma unroll
        for (int i = 0; i < 8; i++) {
            const int f = (i + m2) & 7;
            const float4 h4 = src4[f];
            a0 = fmaf(h4.x, wreg[0*32+i*4+0], a0); a0 = fmaf(h4.y, wreg[0*32+i*4+1], a0);
            a0 = fmaf(h4.z, wreg[0*32+i*4+2], a0); a0 = fmaf(h4.w, wreg[0*32+i*4+3], a0);
            a1 = fmaf(h4.x, wreg[1*32+i*4+0], a1); a1 = fmaf(h4.y, wreg[1*32+i*4+1], a1);
            a1 = fmaf(h4.z, wreg[1*32+i*4+2], a1); a1 = fmaf(h4.w, wreg[1*32+i*4+3], a1);
            a2 = fmaf(h4.x, wreg[2*32+i*4+0], a2); a2 = fmaf(h4.y, wreg[2*32+i*4+1], a2);
            a2 = fmaf(h4.z, wreg[2*32+i*4+2], a2); a2 = fmaf(h4.w, wreg[2*32+i*4+3], a2);
            a3 = fmaf(h4.x, wreg[3*32+i*4+0], a3); a3 = fmaf(h4.y, wreg[3*32+i*4+1], a3);
            a3 = fmaf(h4.z, wreg[3*32+i*4+2], a3); a3 = fmaf(h4.w, wreg[3*32+i*4+3], a3);
        }
        const float r0 = quad_reduce(a0), r1 = quad_reduce(a1);
        const float r2 = quad_reduce(a2), r3 = quad_reduce(a3);
        const float v = ((m == 0) ? r0 : (m == 1) ? r1 : (m == 2) ? r2 : r3) + bias_;
        if (isGi) sI[rowBase + m] = v;
        else      sHh[rowBase + m] = v;
        __syncthreads();                       // gates ready

        if (tid < H) {
            const float r  = sigmoidf_(sI[tid] + sHh[tid]);
            const float z  = sigmoidf_(sI[H + tid] + sHh[H + tid]);
            const float n  = tanhf(sI[2 * H + tid] + r * sHh[2 * H + tid]);
            const float hn = (1.0f - z) * n + z * hprev;
            hprev = hn;
            sH1[tid] = hn;
            hb[(size_t)t * H + tid] = hn;      // overwrite h0[t] with h1[t]
            sHin[tid] = pre;                   // stage h0[t+1]
            if (t + 2 < S) pre = hb[(size_t)(t + 2) * H + tid];
        }
        __syncthreads();                       // state ready for next step
    }
}

// ---------------------------------------------------------------------------
// MLP head, batched over all B*S rows. One wave per block.
// ---------------------------------------------------------------------------
__global__ __launch_bounds__(64)
void head_kernel(const float* __restrict__ h1, const float* __restrict__ x,
                 const float* __restrict__ w1, const float* __restrict__ b1,
                 const float* __restrict__ w2, const float* __restrict__ b2,
                 float* __restrict__ inc, int rows_per_blk)
{
    __shared__ float sC[2][F];
    const int lane = threadIdx.x;

    float wr[F];
#pragma unroll
    for (int f = 0; f < F; f++) wr[f] = w1[lane * F + f];
    const float b1v = b1[lane];
    const float w2v = w2[lane];
    const float b2v = b2[0];

    const int row0 = blockIdx.x * rows_per_blk;

    {
        const int r = row0;
        sC[0][lane]      = h1[(size_t)r * H + lane];
        sC[0][64 + lane] = h1[(size_t)r * H + 64 + lane];
        if (lane < NI) sC[0][H + lane] = x[(size_t)r * NI + lane];
    }
    __syncthreads();

    for (int i = 0; i < rows_per_blk; i++) {
        const int row = row0 + i;
        const int cur = i & 1;
        const int nxt = cur ^ 1;

        float p0 = 0.f, p1 = 0.f, p2 = 0.f;
        if (i + 1 < rows_per_blk) {
            const int rn = row + 1;
            p0 = h1[(size_t)rn * H + lane];
            p1 = h1[(size_t)rn * H + 64 + lane];
            if (lane < NI) p2 = x[(size_t)rn * NI + lane];
        }

        float acc = b1v;
#pragma unroll
        for (int f = 0; f < F; f++) acc += sC[cur][f] * wr[f];

        if (i + 1 < rows_per_blk) {
            sC[nxt][lane]      = p0;
            sC[nxt][64 + lane] = p1;
            if (lane < NI) sC[nxt][H + lane] = p2;
        }

        float v = fmaxf(acc, 0.0f) * w2v;
#pragma unroll
        for (int off = 32; off > 0; off >>= 1) v += __shfl_xor(v, off, 64);

        if (lane == 0) inc[row] = tanhf(v + b2v) * 0.125f;
        __syncthreads();
    }
}

// ---------------------------------------------------------------------------
// Inclusive cumsum over S per batch + initial offset. One block per batch.
// ---------------------------------------------------------------------------
__global__ __launch_bounds__(256)
void cumsum_kernel(const float* __restrict__ inc, const float* __restrict__ init,
                   float* __restrict__ out)
{
    __shared__ float sW[4];
    const int b = blockIdx.x;
    const int tid = threadIdx.x;
    const int lane = tid & 63;
    const int wid = tid >> 6;

    const float* ib = inc + (size_t)b * S;
    float v[16];
#pragma unroll
    for (int i = 0; i < 16; i++) v[i] = ib[tid * 16 + i];

    float run = 0.f;
#pragma unroll
    for (int i = 0; i < 16; i++) { run += v[i]; v[i] = run; }

    float t = run;
#pragma unroll
    for (int off = 1; off < 64; off <<= 1) {
        float u = __shfl_up(t, off, 64);
        if (lane >= off) t += u;
    }
    const float excl = t - run;
    if (lane == 63) sW[wid] = t;
    __syncthreads();

    float wo = 0.f;
#pragma unroll
    for (int w = 0; w < 4; w++) if (w < wid) wo += sW[w];

    const float prefix = wo + excl + init[0];
    float* ob = out + (size_t)b * S;
#pragma unroll
    for (int i = 0; i < 16; i++) ob[tid * 16 + i] = prefix + v[i];
}

// ---------------------------------------------------------------------------
extern "C" void kernel_launch(void* const* d_in, const int* in_sizes, int n_in,
                              void* d_out, int out_size, void* d_ws, size_t ws_size,
                              hipStream_t stream)
{
    const float* x     = (const float*)d_in[0];
    const float* w_ih0 = (const float*)d_in[1];
    const float* w_hh0 = (const float*)d_in[2];
    const float* b_ih0 = (const float*)d_in[3];
    const float* b_hh0 = (const float*)d_in[4];
    const float* w_ih1 = (const float*)d_in[5];
    const float* w_hh1 = (const float*)d_in[6];
    const float* b_ih1 = (const float*)d_in[7];
    const float* b_hh1 = (const float*)d_in[8];
    const float* w1    = (const float*)d_in[9];
    const float* b1    = (const float*)d_in[10];
    const float* w2    = (const float*)d_in[11];
    const float* b2    = (const float*)d_in[12];
    const float* init  = (const float*)d_in[13];
    float* out = (float*)d_out;

    float* hbuf   = (float*)d_ws;                 // B*S*H fp32 = 134 MB
    float* incbuf = hbuf + (size_t)B * S * H;     // B*S fp32  = 1 MB

    hipLaunchKernelGGL(gru_layer0, dim3(B), dim3(G), 0, stream,
                       x, w_ih0, w_hh0, b_ih0, b_hh0, hbuf);
    hipLaunchKernelGGL(gru_layer1, dim3(B), dim3(2 * G), 0, stream,
                       w_ih1, w_hh1, b_ih1, b_hh1, hbuf);
    hipLaunchKernelGGL(head_kernel, dim3((B * S) / 128), dim3(64), 0, stream,
                       hbuf, x, w1, b1, w2, b2, incbuf, 128);
    hipLaunchKernelGGL(cumsum_kernel, dim3(B), dim3(256), 0, stream,
                       incbuf, init, out);
}